// Round 7
// baseline (238.153 us; speedup 1.0000x reference)
//
#include <hip/hip_runtime.h>
#include <hip/hip_bf16.h>

#define BLK 256
#define NPART 8   // partial histograms / slot-counter partitions

typedef unsigned short ushort_t;
typedef unsigned int uint_t;
typedef unsigned long long ull_t;

static __device__ __forceinline__ float bf2f(ushort_t u) {
    return __uint_as_float((uint_t)u << 16);
}
static __device__ __forceinline__ ushort_t f2bf(float f) {
    __hip_bfloat16 h = __float2bfloat16(f);   // RNE
    return *reinterpret_cast<ushort_t*>(&h);
}

// ---------------- graph preprocessing ----------------
// R5: k_edge_deg atomics -> packed u64 partial histograms (75us -> off top-5).
// R6: k_fill's atomicAdd-with-return was 50us (16 serialized RMWs/address).
//     Fix: per-partition slot counters fill8[p*N+d] with bases pbase[p*N+d]
//     derived from the per-partition counts already in hist (contention /8).

__global__ __launch_bounds__(256) void k_init(ull_t* hist, int* fill8, int n8) {
    int i = blockIdx.x * BLK + threadIdx.x;
    if (i < n8) { hist[i] = 0ull; fill8[i] = 0; }
}

__global__ __launch_bounds__(256) void k_edge_deg(const int* __restrict__ eidx,
                                                  const float* __restrict__ ea,
                                                  ull_t* hist, int N, int E) {
    int e = blockIdx.x * BLK + threadIdx.x;
    if (e >= E) return;
    int d = eidx[E + e];
    ull_t v = (1ull << 40) | (ull_t)(ea[e] * 4294967296.0f);
    atomicAdd(&hist[(size_t)(blockIdx.x & (NPART - 1)) * N + d], v);
}

// merge partials -> cnt, dinv, selfn  (self-loop weight 1.0 included)
__global__ __launch_bounds__(256) void k_dinv(const ull_t* __restrict__ hist,
                                              int* cnt, float* dinv, float* selfn, int n) {
    int i = blockIdx.x * BLK + threadIdx.x;
    if (i >= n) return;
    ull_t s = 0;
#pragma unroll
    for (int p = 0; p < NPART; ++p) s += hist[(size_t)p * n + i];
    int c = (int)(s >> 40);
    float dg = 1.0f + (float)(s & ((1ull << 40) - 1)) * (1.0f / 4294967296.0f);
    cnt[i]   = c;
    dinv[i]  = rsqrtf(dg);
    selfn[i] = 1.0f / dg;
}

// ---------------- device-wide exclusive scan (3 passes) ----------------

__global__ __launch_bounds__(256) void k_scan1(const int* __restrict__ cnt,
                                               int* rowptr, int* bsum, int n) {
    __shared__ int tile[256];
    const int t = threadIdx.x;
    const int i = blockIdx.x * 256 + t;
    int v = (i < n) ? cnt[i] : 0;
    tile[t] = v;
    __syncthreads();
    for (int off = 1; off < 256; off <<= 1) {
        int x = (t >= off) ? tile[t - off] : 0;
        __syncthreads();
        tile[t] += x;
        __syncthreads();
    }
    if (i < n) rowptr[i] = tile[t] - v;              // exclusive within block
    if (t == 255) bsum[blockIdx.x] = tile[255];
}

__global__ __launch_bounds__(256) void k_scan2(int* bsum, int* rowptr, int nb, int n) {
    __shared__ int tile[256];
    const int t = threadIdx.x;
    int v = (t < nb) ? bsum[t] : 0;
    tile[t] = v;
    __syncthreads();
    for (int off = 1; off < 256; off <<= 1) {
        int x = (t >= off) ? tile[t - off] : 0;
        __syncthreads();
        tile[t] += x;
        __syncthreads();
    }
    if (t < nb) bsum[t] = tile[t] - v;               // exclusive block offsets
    if (t == 255) rowptr[n] = tile[255];             // grand total = E
}

__global__ __launch_bounds__(256) void k_scan3(int* rowptr, const int* __restrict__ bsum, int n) {
    int i = blockIdx.x * 256 + threadIdx.x;
    if (i < n) rowptr[i] += bsum[blockIdx.x];
}

// per-(partition,node) slot base: pbase[p][i] = rowptr[i] + sum_{q<p} cnt_q[i]
__global__ __launch_bounds__(256) void k_pbase(const ull_t* __restrict__ hist,
                                               const int* __restrict__ rowptr,
                                               int* pbase, int n) {
    int i = blockIdx.x * BLK + threadIdx.x;
    if (i >= n) return;
    int base = rowptr[i];
#pragma unroll
    for (int p = 0; p < NPART; ++p) {
        pbase[(size_t)p * n + i] = base;
        base += (int)(hist[(size_t)p * n + i] >> 40);
    }
}

__global__ __launch_bounds__(256) void k_fill(const int* __restrict__ eidx,
                                              const float* __restrict__ ea,
                                              const float* __restrict__ dinv,
                                              const int* __restrict__ pbase,
                                              int* fill8, int* csr_src, float* csr_val,
                                              int N, int E) {
    int e = blockIdx.x * BLK + threadIdx.x;
    if (e >= E) return;
    int s = eidx[e];
    int d = eidx[E + e];
    size_t slot = (size_t)(blockIdx.x & (NPART - 1)) * N + d;   // same mapping as k_edge_deg
    int pos = pbase[slot] + atomicAdd(&fill8[slot], 1);
    csr_src[pos] = s;
    csr_val[pos] = dinv[s] * ea[e] * dinv[d];
}

// ---------------- per-layer GEMM: C[n,FOUT](bf16) = A[n,FIN](f32) @ W[FIN,FOUT] ----------------

template <int FIN, int FOUT>
__global__ __launch_bounds__(256) void k_gemm(const float* __restrict__ A,
                                              const float* __restrict__ W,
                                              __hip_bfloat16* __restrict__ C, int n) {
    constexpr int TM = 4096 / FOUT;            // rows per block: 32 / 64 / 128
    __shared__ float As[TM * FIN];
    const int tid = threadIdx.x;
    const int tx  = tid % (FOUT / 4);          // 4 cols per thread
    const int ty  = tid / (FOUT / 4);          // 4 rows per thread
    const int row0 = blockIdx.x * TM;

    // stage A tile (vectorized, coalesced)
    const int tot4 = TM * FIN / 4;
    for (int i = tid; i < tot4; i += 256) {
        int r  = i / (FIN / 4);
        int c4 = i % (FIN / 4);
        int gr = row0 + r;
        float4 v = make_float4(0.f, 0.f, 0.f, 0.f);
        if (gr < n) v = ((const float4*)(A + (size_t)gr * FIN))[c4];
        ((float4*)As)[i] = v;
    }
    __syncthreads();

    float acc[4][4] = {};
    // NOTE: partial unroll only. Full unroll hoists all FIN float4 W-loads ->
    // 256 VGPRs + ~650 MB scratch spill traffic (R1 counters).
#pragma unroll 8
    for (int k = 0; k < FIN; ++k) {
        float4 b = *(const float4*)(W + (size_t)k * FOUT + tx * 4);
        float a0 = As[(ty * 4 + 0) * FIN + k];
        float a1 = As[(ty * 4 + 1) * FIN + k];
        float a2 = As[(ty * 4 + 2) * FIN + k];
        float a3 = As[(ty * 4 + 3) * FIN + k];
        acc[0][0] += a0 * b.x; acc[0][1] += a0 * b.y; acc[0][2] += a0 * b.z; acc[0][3] += a0 * b.w;
        acc[1][0] += a1 * b.x; acc[1][1] += a1 * b.y; acc[1][2] += a1 * b.z; acc[1][3] += a1 * b.w;
        acc[2][0] += a2 * b.x; acc[2][1] += a2 * b.y; acc[2][2] += a2 * b.z; acc[2][3] += a2 * b.w;
        acc[3][0] += a3 * b.x; acc[3][1] += a3 * b.y; acc[3][2] += a3 * b.z; acc[3][3] += a3 * b.w;
    }

#pragma unroll
    for (int r = 0; r < 4; ++r) {
        int gr = row0 + ty * 4 + r;
        if (gr < n) {
            ushort4 o = make_ushort4(f2bf(acc[r][0]), f2bf(acc[r][1]),
                                     f2bf(acc[r][2]), f2bf(acc[r][3]));
            *(ushort4*)((ushort_t*)C + (size_t)gr * FOUT + tx * 4) = o;
        }
    }
}

// ---------------- aggregation: out[i] = selfn[i]*H[i] + sum_e csr_val*H[csr_src] + b, (relu) ----
// H is bf16; each lane owns 2 consecutive features. Edge loop manually unrolled x8
// (R4 was latency-bound: 1 gather in flight, HBM at 17%).

template <int FOUT, bool RELU>
__global__ __launch_bounds__(256) void k_agg(const ushort_t* __restrict__ H,
                                             const float* __restrict__ selfn,
                                             const int* __restrict__ rowptr,
                                             const int* __restrict__ csr_src,
                                             const float* __restrict__ csr_val,
                                             const float* __restrict__ bias,
                                             float* __restrict__ out, int n) {
    constexpr int LPN = FOUT / 2;          // lanes per node: 64 / 32 / 16
    constexpr int NPW = 64 / LPN;          // nodes per wave: 1 / 2 / 4
    const int wave = threadIdx.x >> 6;
    const int lane = threadIdx.x & 63;
    const int sub  = lane / LPN;
    const int f2   = lane % LPN;           // feature-pair index
    const int node = (blockIdx.x * 4 + wave) * NPW + sub;
    if (node >= n) return;

    const ushort_t* __restrict__ Hf = H + 2 * f2;   // lane-fixed column base

    const float sn = selfn[node];
    ushort2 hv = *(const ushort2*)(Hf + (size_t)node * FOUT);
    float acc0 = sn * bf2f(hv.x);
    float acc1 = sn * bf2f(hv.y);

    const int e0 = rowptr[node], e1 = rowptr[node + 1];
    int e = e0;
    for (; e + 8 <= e1; e += 8) {
        int   s0 = csr_src[e+0], s1 = csr_src[e+1], s2 = csr_src[e+2], s3 = csr_src[e+3];
        int   s4 = csr_src[e+4], s5 = csr_src[e+5], s6 = csr_src[e+6], s7 = csr_src[e+7];
        float v0 = csr_val[e+0], v1 = csr_val[e+1], v2 = csr_val[e+2], v3 = csr_val[e+3];
        float v4 = csr_val[e+4], v5 = csr_val[e+5], v6 = csr_val[e+6], v7 = csr_val[e+7];
        ushort2 m0 = *(const ushort2*)(Hf + (size_t)s0 * FOUT);
        ushort2 m1 = *(const ushort2*)(Hf + (size_t)s1 * FOUT);
        ushort2 m2 = *(const ushort2*)(Hf + (size_t)s2 * FOUT);
        ushort2 m3 = *(const ushort2*)(Hf + (size_t)s3 * FOUT);
        ushort2 m4 = *(const ushort2*)(Hf + (size_t)s4 * FOUT);
        ushort2 m5 = *(const ushort2*)(Hf + (size_t)s5 * FOUT);
        ushort2 m6 = *(const ushort2*)(Hf + (size_t)s6 * FOUT);
        ushort2 m7 = *(const ushort2*)(Hf + (size_t)s7 * FOUT);
        acc0 += v0 * bf2f(m0.x); acc1 += v0 * bf2f(m0.y);
        acc0 += v1 * bf2f(m1.x); acc1 += v1 * bf2f(m1.y);
        acc0 += v2 * bf2f(m2.x); acc1 += v2 * bf2f(m2.y);
        acc0 += v3 * bf2f(m3.x); acc1 += v3 * bf2f(m3.y);
        acc0 += v4 * bf2f(m4.x); acc1 += v4 * bf2f(m4.y);
        acc0 += v5 * bf2f(m5.x); acc1 += v5 * bf2f(m5.y);
        acc0 += v6 * bf2f(m6.x); acc1 += v6 * bf2f(m6.y);
        acc0 += v7 * bf2f(m7.x); acc1 += v7 * bf2f(m7.y);
    }
    for (; e + 2 <= e1; e += 2) {
        int   s0 = csr_src[e+0], s1 = csr_src[e+1];
        float v0 = csr_val[e+0], v1 = csr_val[e+1];
        ushort2 m0 = *(const ushort2*)(Hf + (size_t)s0 * FOUT);
        ushort2 m1 = *(const ushort2*)(Hf + (size_t)s1 * FOUT);
        acc0 += v0 * bf2f(m0.x); acc1 += v0 * bf2f(m0.y);
        acc0 += v1 * bf2f(m1.x); acc1 += v1 * bf2f(m1.y);
    }
    if (e < e1) {
        int   s0 = csr_src[e];
        float v0 = csr_val[e];
        ushort2 m0 = *(const ushort2*)(Hf + (size_t)s0 * FOUT);
        acc0 += v0 * bf2f(m0.x); acc1 += v0 * bf2f(m0.y);
    }

    acc0 += bias[2 * f2];
    acc1 += bias[2 * f2 + 1];
    if (RELU) { acc0 = fmaxf(acc0, 0.f); acc1 = fmaxf(acc1, 0.f); }
    *(float2*)(out + (size_t)node * FOUT + 2 * f2) = make_float2(acc0, acc1);
}

// ---------------- launch ----------------

extern "C" void kernel_launch(void* const* d_in, const int* in_sizes, int n_in,
                              void* d_out, int out_size, void* d_ws, size_t ws_size,
                              hipStream_t stream) {
    const float* x    = (const float*)d_in[0];
    const int*   eidx = (const int*)d_in[1];
    const float* ea   = (const float*)d_in[2];
    const float* W1   = (const float*)d_in[3];
    const float* b1   = (const float*)d_in[4];
    const float* W2   = (const float*)d_in[5];
    const float* b2   = (const float*)d_in[6];
    const float* W3   = (const float*)d_in[7];
    const float* b3   = (const float*)d_in[8];

    const int N = in_sizes[0] / 128;
    const int E = in_sizes[2];

    char*  base = (char*)d_ws;
    size_t off  = 0;
    auto carve = [&](size_t nbytes) -> void* {
        void* p = base + off;
        off = (off + nbytes + 255) & ~(size_t)255;
        return p;
    };
    ull_t* hist    = (ull_t*)carve((size_t)NPART * N * 8);   // packed cnt|deg partials
    int*   fill8   = (int*)  carve((size_t)NPART * N * 4);   // per-partition slot counters
    int*   pbase   = (int*)  carve((size_t)NPART * N * 4);   // per-partition slot bases
    float* dinv    = (float*)carve((size_t)N * 4);
    float* selfn   = (float*)carve((size_t)N * 4);
    int*   cnt     = (int*)  carve((size_t)N * 4);
    int*   rowptr  = (int*)  carve((size_t)(N + 1) * 4);
    int*   bsum    = (int*)  carve((size_t)256 * 4);
    int*   csr_src = (int*)  carve((size_t)E * 4);
    float* csr_val = (float*)carve((size_t)E * 4);
    ushort_t* bufH = (ushort_t*)carve((size_t)N * 128 * 2);   // bf16 feature table
    float*    bufF = (float*)   carve((size_t)N * 128 * 4);   // f32 agg output
    (void)ws_size;

    const int gN  = (N + BLK - 1) / BLK;   // 196 blocks (fits k_scan2's <=256)
    const int gN8 = (NPART * N + BLK - 1) / BLK;
    const int gE  = (E + BLK - 1) / BLK;

    k_init<<<gN8, BLK, 0, stream>>>(hist, fill8, NPART * N);
    k_edge_deg<<<gE, BLK, 0, stream>>>(eidx, ea, hist, N, E);
    k_dinv<<<gN, BLK, 0, stream>>>(hist, cnt, dinv, selfn, N);
    k_scan1<<<gN, BLK, 0, stream>>>(cnt, rowptr, bsum, N);
    k_scan2<<<1, BLK, 0, stream>>>(bsum, rowptr, gN, N);
    k_scan3<<<gN, BLK, 0, stream>>>(rowptr, bsum, N);
    k_pbase<<<gN, BLK, 0, stream>>>(hist, rowptr, pbase, N);
    k_fill<<<gE, BLK, 0, stream>>>(eidx, ea, dinv, pbase, fill8, csr_src, csr_val, N, E);

    // layer 1: 128 -> 128, relu
    k_gemm<128, 128><<<(N + 31) / 32, BLK, 0, stream>>>(x, W1, (__hip_bfloat16*)bufH, N);
    k_agg<128, true><<<(N + 3) / 4, BLK, 0, stream>>>(bufH, selfn, rowptr, csr_src, csr_val, b1, bufF, N);

    // layer 2: 128 -> 64, relu
    k_gemm<128, 64><<<(N + 63) / 64, BLK, 0, stream>>>(bufF, W2, (__hip_bfloat16*)bufH, N);
    k_agg<64, true><<<(N + 7) / 8, BLK, 0, stream>>>(bufH, selfn, rowptr, csr_src, csr_val, b2, bufF, N);

    // layer 3: 64 -> 32, no relu
    k_gemm<64, 32><<<(N + 127) / 128, BLK, 0, stream>>>(bufF, W3, (__hip_bfloat16*)bufH, N);
    k_agg<32, false><<<(N + 15) / 16, BLK, 0, stream>>>(bufH, selfn, rowptr, csr_src, csr_val, b3, (float*)d_out, N);
}

// Round 8
// 195.075 us; speedup vs baseline: 1.2208x; 1.2208x over previous
//
#include <hip/hip_runtime.h>
#include <hip/hip_bf16.h>

#define BLK 256
#define SCAT_NB 512        // blocks in the binning scatter pass
#define BIN_SHIFT 8        // 256 nodes per bin

typedef unsigned short ushort_t;
typedef unsigned int uint_t;
typedef unsigned long long ull_t;

static __device__ __forceinline__ float bf2f(ushort_t u) {
    return __uint_as_float((uint_t)u << 16);
}
static __device__ __forceinline__ ushort_t f2bf(float f) {
    __hip_bfloat16 h = __float2bfloat16(f);   // RNE
    return *reinterpret_cast<ushort_t*>(&h);
}

// ---------------- graph preprocessing: atomic-free binned CSR build ----------------
// R7 post-mortem: k_fill (atomic slot claim + scattered 4B stores) had 12x write
// amplification (79MB vs 6.4MB logical) and k_edge_deg ~45us of scattered u64
// atomics. Preprocessing chain = ~115us of 238. Replaced with two-level counting
// sort: bin by dst>>8 (196 bins x 256 nodes), per-bin LDS histogram (cnt + packed
// fixed-point deg), then per-bin emit into CONTIGUOUS csr regions. Zero global atomics.

// pass A: per-(block,bin) edge counts
__global__ __launch_bounds__(256) void k_bin_count(const int* __restrict__ eidx,
                                                   int* __restrict__ bcnt,
                                                   int nbins, int epb, int E) {
    __shared__ int h[256];
    const int t = threadIdx.x;
    h[t] = 0;
    __syncthreads();
    const int base = blockIdx.x * epb;
    const int lim  = min(base + epb, E);
    for (int e = base + t; e < lim; e += 256)
        atomicAdd(&h[eidx[E + e] >> BIN_SHIFT], 1);
    __syncthreads();
    if (t < nbins) bcnt[(size_t)t * SCAT_NB + blockIdx.x] = h[t];
}

// pass B: scatter edges into bin-major buffers (positions from scanned bcnt)
__global__ __launch_bounds__(256) void k_bin_scatter(const int* __restrict__ eidx,
                                                     const float* __restrict__ ea,
                                                     const int* __restrict__ ebofs,
                                                     int2* __restrict__ binned_sd,
                                                     float* __restrict__ binned_ea,
                                                     int nbins, int epb, int E) {
    __shared__ int h[256];
    __shared__ int lofs[256];
    const int t = threadIdx.x;
    h[t] = 0;
    if (t < nbins) lofs[t] = ebofs[(size_t)t * SCAT_NB + blockIdx.x];
    __syncthreads();
    const int base = blockIdx.x * epb;
    const int lim  = min(base + epb, E);
    for (int e = base + t; e < lim; e += 256) {
        int s = eidx[e];
        int d = eidx[E + e];
        float w = ea[e];
        int bin = d >> BIN_SHIFT;
        int r = atomicAdd(&h[bin], 1);      // LDS-local rank
        int pos = lofs[bin] + r;
        binned_sd[pos] = make_int2(s, d);
        binned_ea[pos] = w;
    }
}

// pass C: per-bin node histogram (cnt + fixed-point weighted deg) + dinv/selfn
__global__ __launch_bounds__(256) void k_bin_hist(const int2* __restrict__ binned_sd,
                                                  const float* __restrict__ binned_ea,
                                                  const int* __restrict__ ebofs,
                                                  int* __restrict__ cnt,
                                                  float* __restrict__ dinv,
                                                  float* __restrict__ selfn,
                                                  int nbins, int N, int E) {
    __shared__ ull_t hs[256];
    const int t = threadIdx.x;
    const int b = blockIdx.x;
    hs[t] = 0ull;
    __syncthreads();
    const int start = ebofs[(size_t)b * SCAT_NB];
    const int end   = (b + 1 < nbins) ? ebofs[(size_t)(b + 1) * SCAT_NB] : E;
    for (int i = start + t; i < end; i += 256) {
        int d = binned_sd[i].y;
        float w = binned_ea[i];
        atomicAdd(&hs[d & 255], (1ull << 40) | (ull_t)(w * 4294967296.0f));
    }
    __syncthreads();
    const int node = (b << BIN_SHIFT) + t;
    if (node < N) {
        ull_t s = hs[t];
        float dg = 1.0f + (float)(s & ((1ull << 40) - 1)) * (1.0f / 4294967296.0f);
        cnt[node]   = (int)(s >> 40);
        dinv[node]  = rsqrtf(dg);
        selfn[node] = 1.0f / dg;
    }
}

// pass D: per-bin emit into final (contiguous) CSR region
__global__ __launch_bounds__(256) void k_bin_emit(const int2* __restrict__ binned_sd,
                                                  const float* __restrict__ binned_ea,
                                                  const int* __restrict__ ebofs,
                                                  const int* __restrict__ rowptr,
                                                  const float* __restrict__ dinv,
                                                  int* __restrict__ csr_src,
                                                  float* __restrict__ csr_val,
                                                  int nbins, int E) {
    __shared__ int c2[256];
    const int t = threadIdx.x;
    const int b = blockIdx.x;
    c2[t] = 0;
    __syncthreads();
    const int start = ebofs[(size_t)b * SCAT_NB];
    const int end   = (b + 1 < nbins) ? ebofs[(size_t)(b + 1) * SCAT_NB] : E;
    for (int i = start + t; i < end; i += 256) {
        int2 sd = binned_sd[i];
        float w = binned_ea[i];
        int r = atomicAdd(&c2[sd.y & 255], 1);   // LDS-local rank within node
        int pos = rowptr[sd.y] + r;
        csr_src[pos] = sd.x;
        csr_val[pos] = dinv[sd.x] * w * dinv[sd.y];
    }
}

// ---------------- device-wide exclusive scans ----------------

__global__ __launch_bounds__(256) void k_scan1(const int* __restrict__ cnt,
                                               int* rowptr, int* bsum, int n) {
    __shared__ int tile[256];
    const int t = threadIdx.x;
    const int i = blockIdx.x * 256 + t;
    int v = (i < n) ? cnt[i] : 0;
    tile[t] = v;
    __syncthreads();
    for (int off = 1; off < 256; off <<= 1) {
        int x = (t >= off) ? tile[t - off] : 0;
        __syncthreads();
        tile[t] += x;
        __syncthreads();
    }
    if (i < n) rowptr[i] = tile[t] - v;              // exclusive within block
    if (t == 255) bsum[blockIdx.x] = tile[255];
}

// single block, nb <= 256
__global__ __launch_bounds__(256) void k_scan2(int* bsum, int* rowptr, int nb, int n) {
    __shared__ int tile[256];
    const int t = threadIdx.x;
    int v = (t < nb) ? bsum[t] : 0;
    tile[t] = v;
    __syncthreads();
    for (int off = 1; off < 256; off <<= 1) {
        int x = (t >= off) ? tile[t - off] : 0;
        __syncthreads();
        tile[t] += x;
        __syncthreads();
    }
    if (t < nb) bsum[t] = tile[t] - v;               // exclusive block offsets
    if (t == 255) rowptr[n] = tile[255];             // grand total = E
}

// single block, arbitrary n (serial tiles with carry), in-place exclusive
__global__ __launch_bounds__(256) void k_scan2x(int* a, int n) {
    __shared__ int tile[256];
    __shared__ int carry_s;
    const int t = threadIdx.x;
    if (t == 0) carry_s = 0;
    __syncthreads();
    for (int base = 0; base < n; base += 256) {
        int i = base + t;
        int v = (i < n) ? a[i] : 0;
        tile[t] = v;
        __syncthreads();
        for (int off = 1; off < 256; off <<= 1) {
            int x = (t >= off) ? tile[t - off] : 0;
            __syncthreads();
            tile[t] += x;
            __syncthreads();
        }
        int carry = carry_s;
        if (i < n) a[i] = carry + tile[t] - v;
        __syncthreads();
        if (t == 255) carry_s = carry + tile[255];
        __syncthreads();
    }
}

__global__ __launch_bounds__(256) void k_scan3(int* rowptr, const int* __restrict__ bsum, int n) {
    int i = blockIdx.x * 256 + threadIdx.x;
    if (i < n) rowptr[i] += bsum[blockIdx.x];
}

// ---------------- per-layer GEMM: C[n,FOUT](bf16) = A[n,FIN](f32) @ W[FIN,FOUT] ----------------

template <int FIN, int FOUT>
__global__ __launch_bounds__(256) void k_gemm(const float* __restrict__ A,
                                              const float* __restrict__ W,
                                              __hip_bfloat16* __restrict__ C, int n) {
    constexpr int TM = 4096 / FOUT;            // rows per block: 32 / 64 / 128
    __shared__ float As[TM * FIN];
    const int tid = threadIdx.x;
    const int tx  = tid % (FOUT / 4);          // 4 cols per thread
    const int ty  = tid / (FOUT / 4);          // 4 rows per thread
    const int row0 = blockIdx.x * TM;

    const int tot4 = TM * FIN / 4;
    for (int i = tid; i < tot4; i += 256) {
        int r  = i / (FIN / 4);
        int c4 = i % (FIN / 4);
        int gr = row0 + r;
        float4 v = make_float4(0.f, 0.f, 0.f, 0.f);
        if (gr < n) v = ((const float4*)(A + (size_t)gr * FIN))[c4];
        ((float4*)As)[i] = v;
    }
    __syncthreads();

    float acc[4][4] = {};
    // NOTE: partial unroll only. Full unroll hoists all FIN float4 W-loads ->
    // 256 VGPRs + ~650 MB scratch spill traffic (R1 counters).
#pragma unroll 8
    for (int k = 0; k < FIN; ++k) {
        float4 b = *(const float4*)(W + (size_t)k * FOUT + tx * 4);
        float a0 = As[(ty * 4 + 0) * FIN + k];
        float a1 = As[(ty * 4 + 1) * FIN + k];
        float a2 = As[(ty * 4 + 2) * FIN + k];
        float a3 = As[(ty * 4 + 3) * FIN + k];
        acc[0][0] += a0 * b.x; acc[0][1] += a0 * b.y; acc[0][2] += a0 * b.z; acc[0][3] += a0 * b.w;
        acc[1][0] += a1 * b.x; acc[1][1] += a1 * b.y; acc[1][2] += a1 * b.z; acc[1][3] += a1 * b.w;
        acc[2][0] += a2 * b.x; acc[2][1] += a2 * b.y; acc[2][2] += a2 * b.z; acc[2][3] += a2 * b.w;
        acc[3][0] += a3 * b.x; acc[3][1] += a3 * b.y; acc[3][2] += a3 * b.z; acc[3][3] += a3 * b.w;
    }

#pragma unroll
    for (int r = 0; r < 4; ++r) {
        int gr = row0 + ty * 4 + r;
        if (gr < n) {
            ushort4 o = make_ushort4(f2bf(acc[r][0]), f2bf(acc[r][1]),
                                     f2bf(acc[r][2]), f2bf(acc[r][3]));
            *(ushort4*)((ushort_t*)C + (size_t)gr * FOUT + tx * 4) = o;
        }
    }
}

// ---------------- aggregation (bf16 H, x8-unrolled gather loop) ----------------

template <int FOUT, bool RELU>
__global__ __launch_bounds__(256) void k_agg(const ushort_t* __restrict__ H,
                                             const float* __restrict__ selfn,
                                             const int* __restrict__ rowptr,
                                             const int* __restrict__ csr_src,
                                             const float* __restrict__ csr_val,
                                             const float* __restrict__ bias,
                                             float* __restrict__ out, int n) {
    constexpr int LPN = FOUT / 2;          // lanes per node: 64 / 32 / 16
    constexpr int NPW = 64 / LPN;          // nodes per wave: 1 / 2 / 4
    const int wave = threadIdx.x >> 6;
    const int lane = threadIdx.x & 63;
    const int sub  = lane / LPN;
    const int f2   = lane % LPN;           // feature-pair index
    const int node = (blockIdx.x * 4 + wave) * NPW + sub;
    if (node >= n) return;

    const ushort_t* __restrict__ Hf = H + 2 * f2;   // lane-fixed column base

    const float sn = selfn[node];
    ushort2 hv = *(const ushort2*)(Hf + (size_t)node * FOUT);
    float acc0 = sn * bf2f(hv.x);
    float acc1 = sn * bf2f(hv.y);

    const int e0 = rowptr[node], e1 = rowptr[node + 1];
    int e = e0;
    for (; e + 8 <= e1; e += 8) {
        int   s0 = csr_src[e+0], s1 = csr_src[e+1], s2 = csr_src[e+2], s3 = csr_src[e+3];
        int   s4 = csr_src[e+4], s5 = csr_src[e+5], s6 = csr_src[e+6], s7 = csr_src[e+7];
        float v0 = csr_val[e+0], v1 = csr_val[e+1], v2 = csr_val[e+2], v3 = csr_val[e+3];
        float v4 = csr_val[e+4], v5 = csr_val[e+5], v6 = csr_val[e+6], v7 = csr_val[e+7];
        ushort2 m0 = *(const ushort2*)(Hf + (size_t)s0 * FOUT);
        ushort2 m1 = *(const ushort2*)(Hf + (size_t)s1 * FOUT);
        ushort2 m2 = *(const ushort2*)(Hf + (size_t)s2 * FOUT);
        ushort2 m3 = *(const ushort2*)(Hf + (size_t)s3 * FOUT);
        ushort2 m4 = *(const ushort2*)(Hf + (size_t)s4 * FOUT);
        ushort2 m5 = *(const ushort2*)(Hf + (size_t)s5 * FOUT);
        ushort2 m6 = *(const ushort2*)(Hf + (size_t)s6 * FOUT);
        ushort2 m7 = *(const ushort2*)(Hf + (size_t)s7 * FOUT);
        acc0 += v0 * bf2f(m0.x); acc1 += v0 * bf2f(m0.y);
        acc0 += v1 * bf2f(m1.x); acc1 += v1 * bf2f(m1.y);
        acc0 += v2 * bf2f(m2.x); acc1 += v2 * bf2f(m2.y);
        acc0 += v3 * bf2f(m3.x); acc1 += v3 * bf2f(m3.y);
        acc0 += v4 * bf2f(m4.x); acc1 += v4 * bf2f(m4.y);
        acc0 += v5 * bf2f(m5.x); acc1 += v5 * bf2f(m5.y);
        acc0 += v6 * bf2f(m6.x); acc1 += v6 * bf2f(m6.y);
        acc0 += v7 * bf2f(m7.x); acc1 += v7 * bf2f(m7.y);
    }
    for (; e + 2 <= e1; e += 2) {
        int   s0 = csr_src[e+0], s1 = csr_src[e+1];
        float v0 = csr_val[e+0], v1 = csr_val[e+1];
        ushort2 m0 = *(const ushort2*)(Hf + (size_t)s0 * FOUT);
        ushort2 m1 = *(const ushort2*)(Hf + (size_t)s1 * FOUT);
        acc0 += v0 * bf2f(m0.x); acc1 += v0 * bf2f(m0.y);
        acc0 += v1 * bf2f(m1.x); acc1 += v1 * bf2f(m1.y);
    }
    if (e < e1) {
        int   s0 = csr_src[e];
        float v0 = csr_val[e];
        ushort2 m0 = *(const ushort2*)(Hf + (size_t)s0 * FOUT);
        acc0 += v0 * bf2f(m0.x); acc1 += v0 * bf2f(m0.y);
    }

    acc0 += bias[2 * f2];
    acc1 += bias[2 * f2 + 1];
    if (RELU) { acc0 = fmaxf(acc0, 0.f); acc1 = fmaxf(acc1, 0.f); }
    *(float2*)(out + (size_t)node * FOUT + 2 * f2) = make_float2(acc0, acc1);
}

// ---------------- launch ----------------

extern "C" void kernel_launch(void* const* d_in, const int* in_sizes, int n_in,
                              void* d_out, int out_size, void* d_ws, size_t ws_size,
                              hipStream_t stream) {
    const float* x    = (const float*)d_in[0];
    const int*   eidx = (const int*)d_in[1];
    const float* ea   = (const float*)d_in[2];
    const float* W1   = (const float*)d_in[3];
    const float* b1   = (const float*)d_in[4];
    const float* W2   = (const float*)d_in[5];
    const float* b2   = (const float*)d_in[6];
    const float* W3   = (const float*)d_in[7];
    const float* b3   = (const float*)d_in[8];

    const int N = in_sizes[0] / 128;
    const int E = in_sizes[2];

    const int nbins = (N + 255) >> BIN_SHIFT;            // 196 for N=50000 (<=256)
    const int epb   = (E + SCAT_NB - 1) / SCAT_NB;       // edges per scatter block
    const int nbc   = nbins * SCAT_NB;                   // bcnt/ebofs length
    const int gBC   = (nbc + BLK - 1) / BLK;             // 392

    char*  base = (char*)d_ws;
    size_t off  = 0;
    auto carve = [&](size_t nbytes) -> void* {
        void* p = base + off;
        off = (off + nbytes + 255) & ~(size_t)255;
        return p;
    };
    int*   bcnt      = (int*)  carve((size_t)nbc * 4);
    int*   ebofs     = (int*)  carve((size_t)nbc * 4);
    int*   bsumB     = (int*)  carve((size_t)512 * 4);
    int2*  binned_sd = (int2*) carve((size_t)E * 8);
    float* binned_ea = (float*)carve((size_t)E * 4);
    float* dinv      = (float*)carve((size_t)N * 4);
    float* selfn     = (float*)carve((size_t)N * 4);
    int*   cnt       = (int*)  carve((size_t)N * 4);
    int*   rowptr    = (int*)  carve((size_t)(N + 1) * 4);
    int*   bsum      = (int*)  carve((size_t)256 * 4);
    int*   csr_src   = (int*)  carve((size_t)E * 4);
    float* csr_val   = (float*)carve((size_t)E * 4);
    ushort_t* bufH   = (ushort_t*)carve((size_t)N * 128 * 2);   // bf16 feature table
    float*    bufF   = (float*)   carve((size_t)N * 128 * 4);   // f32 agg output
    (void)ws_size;

    const int gN = (N + BLK - 1) / BLK;   // 196 blocks (fits k_scan2's <=256)

    // binned CSR build (no global atomics)
    k_bin_count<<<SCAT_NB, BLK, 0, stream>>>(eidx, bcnt, nbins, epb, E);
    k_scan1<<<gBC, BLK, 0, stream>>>(bcnt, ebofs, bsumB, nbc);
    k_scan2x<<<1, BLK, 0, stream>>>(bsumB, gBC);
    k_scan3<<<gBC, BLK, 0, stream>>>(ebofs, bsumB, nbc);
    k_bin_scatter<<<SCAT_NB, BLK, 0, stream>>>(eidx, ea, ebofs, binned_sd, binned_ea, nbins, epb, E);
    k_bin_hist<<<nbins, BLK, 0, stream>>>(binned_sd, binned_ea, ebofs, cnt, dinv, selfn, nbins, N, E);
    k_scan1<<<gN, BLK, 0, stream>>>(cnt, rowptr, bsum, N);
    k_scan2<<<1, BLK, 0, stream>>>(bsum, rowptr, gN, N);
    k_scan3<<<gN, BLK, 0, stream>>>(rowptr, bsum, N);
    k_bin_emit<<<nbins, BLK, 0, stream>>>(binned_sd, binned_ea, ebofs, rowptr, dinv,
                                          csr_src, csr_val, nbins, E);

    // layer 1: 128 -> 128, relu
    k_gemm<128, 128><<<(N + 31) / 32, BLK, 0, stream>>>(x, W1, (__hip_bfloat16*)bufH, N);
    k_agg<128, true><<<(N + 3) / 4, BLK, 0, stream>>>(bufH, selfn, rowptr, csr_src, csr_val, b1, bufF, N);

    // layer 2: 128 -> 64, relu
    k_gemm<128, 64><<<(N + 63) / 64, BLK, 0, stream>>>(bufF, W2, (__hip_bfloat16*)bufH, N);
    k_agg<64, true><<<(N + 7) / 8, BLK, 0, stream>>>(bufH, selfn, rowptr, csr_src, csr_val, b2, bufF, N);

    // layer 3: 64 -> 32, no relu
    k_gemm<64, 32><<<(N + 127) / 128, BLK, 0, stream>>>(bufF, W3, (__hip_bfloat16*)bufH, N);
    k_agg<32, false><<<(N + 15) / 16, BLK, 0, stream>>>(bufH, selfn, rowptr, csr_src, csr_val, b3, (float*)d_out, N);
}

// Round 9
// 184.807 us; speedup vs baseline: 1.2887x; 1.0556x over previous
//
#include <hip/hip_runtime.h>
#include <hip/hip_bf16.h>

#define BLK 256
#define SCAT_NB 512        // blocks in the binning scatter pass
#define BIN_SHIFT 8        // 256 nodes per bin

typedef unsigned short ushort_t;
typedef unsigned int uint_t;
typedef unsigned long long ull_t;
typedef __attribute__((ext_vector_type(8))) short bf16x8;
typedef __attribute__((ext_vector_type(4))) float f32x4;

static __device__ __forceinline__ float bf2f(ushort_t u) {
    return __uint_as_float((uint_t)u << 16);
}
static __device__ __forceinline__ ushort_t f2bf(float f) {
    __hip_bfloat16 h = __float2bfloat16(f);   // RNE
    return *reinterpret_cast<ushort_t*>(&h);
}

// ---------------- graph preprocessing: atomic-free binned CSR build (R8: 238->195us) ----

// pass A: per-(block,bin) edge counts
__global__ __launch_bounds__(256) void k_bin_count(const int* __restrict__ eidx,
                                                   int* __restrict__ bcnt,
                                                   int nbins, int epb, int E) {
    __shared__ int h[256];
    const int t = threadIdx.x;
    h[t] = 0;
    __syncthreads();
    const int base = blockIdx.x * epb;
    const int lim  = min(base + epb, E);
    for (int e = base + t; e < lim; e += 256)
        atomicAdd(&h[eidx[E + e] >> BIN_SHIFT], 1);
    __syncthreads();
    if (t < nbins) bcnt[(size_t)t * SCAT_NB + blockIdx.x] = h[t];
}

// pass B: scatter edges into bin-major buffers (positions from scanned bcnt)
__global__ __launch_bounds__(256) void k_bin_scatter(const int* __restrict__ eidx,
                                                     const float* __restrict__ ea,
                                                     const int* __restrict__ ebofs,
                                                     int2* __restrict__ binned_sd,
                                                     float* __restrict__ binned_ea,
                                                     int nbins, int epb, int E) {
    __shared__ int h[256];
    __shared__ int lofs[256];
    const int t = threadIdx.x;
    h[t] = 0;
    if (t < nbins) lofs[t] = ebofs[(size_t)t * SCAT_NB + blockIdx.x];
    __syncthreads();
    const int base = blockIdx.x * epb;
    const int lim  = min(base + epb, E);
    for (int e = base + t; e < lim; e += 256) {
        int s = eidx[e];
        int d = eidx[E + e];
        float w = ea[e];
        int bin = d >> BIN_SHIFT;
        int r = atomicAdd(&h[bin], 1);      // LDS-local rank
        int pos = lofs[bin] + r;
        binned_sd[pos] = make_int2(s, d);
        binned_ea[pos] = w;
    }
}

// pass C: per-bin node histogram (cnt + fixed-point weighted deg) + dinv/selfn
__global__ __launch_bounds__(256) void k_bin_hist(const int2* __restrict__ binned_sd,
                                                  const float* __restrict__ binned_ea,
                                                  const int* __restrict__ ebofs,
                                                  int* __restrict__ cnt,
                                                  float* __restrict__ dinv,
                                                  float* __restrict__ selfn,
                                                  int nbins, int N, int E) {
    __shared__ ull_t hs[256];
    const int t = threadIdx.x;
    const int b = blockIdx.x;
    hs[t] = 0ull;
    __syncthreads();
    const int start = ebofs[(size_t)b * SCAT_NB];
    const int end   = (b + 1 < nbins) ? ebofs[(size_t)(b + 1) * SCAT_NB] : E;
    for (int i = start + t; i < end; i += 256) {
        int d = binned_sd[i].y;
        float w = binned_ea[i];
        atomicAdd(&hs[d & 255], (1ull << 40) | (ull_t)(w * 4294967296.0f));
    }
    __syncthreads();
    const int node = (b << BIN_SHIFT) + t;
    if (node < N) {
        ull_t s = hs[t];
        float dg = 1.0f + (float)(s & ((1ull << 40) - 1)) * (1.0f / 4294967296.0f);
        cnt[node]   = (int)(s >> 40);
        dinv[node]  = rsqrtf(dg);
        selfn[node] = 1.0f / dg;
    }
}

// pass D: per-bin emit into final (contiguous) CSR region
__global__ __launch_bounds__(256) void k_bin_emit(const int2* __restrict__ binned_sd,
                                                  const float* __restrict__ binned_ea,
                                                  const int* __restrict__ ebofs,
                                                  const int* __restrict__ rowptr,
                                                  const float* __restrict__ dinv,
                                                  int* __restrict__ csr_src,
                                                  float* __restrict__ csr_val,
                                                  int nbins, int E) {
    __shared__ int c2[256];
    const int t = threadIdx.x;
    const int b = blockIdx.x;
    c2[t] = 0;
    __syncthreads();
    const int start = ebofs[(size_t)b * SCAT_NB];
    const int end   = (b + 1 < nbins) ? ebofs[(size_t)(b + 1) * SCAT_NB] : E;
    for (int i = start + t; i < end; i += 256) {
        int2 sd = binned_sd[i];
        float w = binned_ea[i];
        int r = atomicAdd(&c2[sd.y & 255], 1);   // LDS-local rank within node
        int pos = rowptr[sd.y] + r;
        csr_src[pos] = sd.x;
        csr_val[pos] = dinv[sd.x] * w * dinv[sd.y];
    }
}

// ---------------- device-wide exclusive scans ----------------

__global__ __launch_bounds__(256) void k_scan1(const int* __restrict__ cnt,
                                               int* rowptr, int* bsum, int n) {
    __shared__ int tile[256];
    const int t = threadIdx.x;
    const int i = blockIdx.x * 256 + t;
    int v = (i < n) ? cnt[i] : 0;
    tile[t] = v;
    __syncthreads();
    for (int off = 1; off < 256; off <<= 1) {
        int x = (t >= off) ? tile[t - off] : 0;
        __syncthreads();
        tile[t] += x;
        __syncthreads();
    }
    if (i < n) rowptr[i] = tile[t] - v;              // exclusive within block
    if (t == 255) bsum[blockIdx.x] = tile[255];
}

// single block, nb <= 256
__global__ __launch_bounds__(256) void k_scan2(int* bsum, int* rowptr, int nb, int n) {
    __shared__ int tile[256];
    const int t = threadIdx.x;
    int v = (t < nb) ? bsum[t] : 0;
    tile[t] = v;
    __syncthreads();
    for (int off = 1; off < 256; off <<= 1) {
        int x = (t >= off) ? tile[t - off] : 0;
        __syncthreads();
        tile[t] += x;
        __syncthreads();
    }
    if (t < nb) bsum[t] = tile[t] - v;               // exclusive block offsets
    if (t == 255) rowptr[n] = tile[255];             // grand total = E
}

// single block, arbitrary n (serial tiles with carry), in-place exclusive
__global__ __launch_bounds__(256) void k_scan2x(int* a, int n) {
    __shared__ int tile[256];
    __shared__ int carry_s;
    const int t = threadIdx.x;
    if (t == 0) carry_s = 0;
    __syncthreads();
    for (int base = 0; base < n; base += 256) {
        int i = base + t;
        int v = (i < n) ? a[i] : 0;
        tile[t] = v;
        __syncthreads();
        for (int off = 1; off < 256; off <<= 1) {
            int x = (t >= off) ? tile[t - off] : 0;
            __syncthreads();
            tile[t] += x;
            __syncthreads();
        }
        int carry = carry_s;
        if (i < n) a[i] = carry + tile[t] - v;
        __syncthreads();
        if (t == 255) carry_s = carry + tile[255];
        __syncthreads();
    }
}

__global__ __launch_bounds__(256) void k_scan3(int* rowptr, const int* __restrict__ bsum, int n) {
    int i = blockIdx.x * 256 + threadIdx.x;
    if (i < n) rowptr[i] += bsum[blockIdx.x];
}

// ---------------- dtype conversion helpers ----------------

// f32 -> bf16, 4 elements per thread
__global__ __launch_bounds__(256) void k_cvt(const float* __restrict__ in,
                                             ushort_t* __restrict__ out, int n4) {
    int i = blockIdx.x * 256 + threadIdx.x;
    if (i >= n4) return;
    float4 v = ((const float4*)in)[i];
    ushort4 o = make_ushort4(f2bf(v.x), f2bf(v.y), f2bf(v.z), f2bf(v.w));
    ((ushort4*)out)[i] = o;
}

// W[fin][fout] f32 -> Wt[fout][fin] bf16 (transpose so B-fragment k's are contiguous)
__global__ __launch_bounds__(256) void k_wconv(const float* __restrict__ W,
                                               ushort_t* __restrict__ Wt, int fin, int fout) {
    int i = blockIdx.x * 256 + threadIdx.x;
    if (i >= fin * fout) return;
    int r = i / fout, c = i % fout;
    Wt[(size_t)c * fin + r] = f2bf(W[i]);
}

// ---------------- MFMA GEMM: C[n,FOUT](bf16) = A[n,FIN](bf16) @ Wt[FOUT,FIN]^T ----------------
// R8 post-mortem: f32 VALU GEMMs were 42/21/10us (39 TF, MfmaUtil=0). bf16 MFMA path:
// mfma_f32_16x16x32_bf16, A-frag row=lane&15 k=(lane>>4)*8+j (contiguous bf16x8 load),
// B-frag col=lane&15 same k from pre-transposed Wt, C/D col=lane&15 row=(lane>>4)*4+reg
// (m89-verified mapping). One wave = 16 rows x FOUT.

template <int FIN, int FOUT>
__global__ __launch_bounds__(256) void k_gemm_mfma(const ushort_t* __restrict__ A,
                                                   const ushort_t* __restrict__ Wt,
                                                   ushort_t* __restrict__ C, int n) {
    constexpr int NT = FOUT / 16;      // col tiles
    constexpr int NK = FIN / 32;       // K steps
    const int wave = threadIdx.x >> 6;
    const int lane = threadIdx.x & 63;
    const int r0 = (blockIdx.x * 4 + wave) * 16;
    if (r0 >= n) return;

    const int l15 = lane & 15;
    const int kg  = lane >> 4;
    const int arow = min(r0 + l15, n - 1);     // tail clamp; bad rows never stored

    f32x4 acc[NT];
#pragma unroll
    for (int c = 0; c < NT; ++c) acc[c] = (f32x4)(0.0f);

    const ushort_t* Ap = A + (size_t)arow * FIN + kg * 8;
    const ushort_t* Bp = Wt + (size_t)l15 * FIN + kg * 8;

#pragma unroll 1   // keep rolled: full unroll hoists all B loads -> spill (R1 lesson)
    for (int ks = 0; ks < NK; ++ks) {
        bf16x8 a = *(const bf16x8*)(Ap + ks * 32);
#pragma unroll
        for (int c = 0; c < NT; ++c) {
            bf16x8 b = *(const bf16x8*)(Bp + (size_t)c * 16 * FIN + ks * 32);
            acc[c] = __builtin_amdgcn_mfma_f32_16x16x32_bf16(a, b, acc[c], 0, 0, 0);
        }
    }

    const int rbase = r0 + kg * 4;
#pragma unroll
    for (int c = 0; c < NT; ++c) {
#pragma unroll
        for (int j = 0; j < 4; ++j) {
            int row = rbase + j;
            if (row < n) C[(size_t)row * FOUT + c * 16 + l15] = f2bf(acc[c][j]);
        }
    }
}

// ---------------- aggregation (bf16 H, x8-unrolled gather loop) ----------------
// OBF16: layers 1/2 write bf16 (feeds next MFMA GEMM; same rounding point as
// quantize-in-gemm, halves traffic). Final layer writes f32 to d_out.

template <int FOUT, bool RELU, bool OBF16>
__global__ __launch_bounds__(256) void k_agg(const ushort_t* __restrict__ H,
                                             const float* __restrict__ selfn,
                                             const int* __restrict__ rowptr,
                                             const int* __restrict__ csr_src,
                                             const float* __restrict__ csr_val,
                                             const float* __restrict__ bias,
                                             void* __restrict__ outv, int n) {
    constexpr int LPN = FOUT / 2;          // lanes per node: 64 / 32 / 16
    constexpr int NPW = 64 / LPN;          // nodes per wave: 1 / 2 / 4
    const int wave = threadIdx.x >> 6;
    const int lane = threadIdx.x & 63;
    const int sub  = lane / LPN;
    const int f2   = lane % LPN;           // feature-pair index
    const int node = (blockIdx.x * 4 + wave) * NPW + sub;
    if (node >= n) return;

    const ushort_t* __restrict__ Hf = H + 2 * f2;   // lane-fixed column base

    const float sn = selfn[node];
    ushort2 hv = *(const ushort2*)(Hf + (size_t)node * FOUT);
    float acc0 = sn * bf2f(hv.x);
    float acc1 = sn * bf2f(hv.y);

    const int e0 = rowptr[node], e1 = rowptr[node + 1];
    int e = e0;
    for (; e + 8 <= e1; e += 8) {
        int   s0 = csr_src[e+0], s1 = csr_src[e+1], s2 = csr_src[e+2], s3 = csr_src[e+3];
        int   s4 = csr_src[e+4], s5 = csr_src[e+5], s6 = csr_src[e+6], s7 = csr_src[e+7];
        float v0 = csr_val[e+0], v1 = csr_val[e+1], v2 = csr_val[e+2], v3 = csr_val[e+3];
        float v4 = csr_val[e+4], v5 = csr_val[e+5], v6 = csr_val[e+6], v7 = csr_val[e+7];
        ushort2 m0 = *(const ushort2*)(Hf + (size_t)s0 * FOUT);
        ushort2 m1 = *(const ushort2*)(Hf + (size_t)s1 * FOUT);
        ushort2 m2 = *(const ushort2*)(Hf + (size_t)s2 * FOUT);
        ushort2 m3 = *(const ushort2*)(Hf + (size_t)s3 * FOUT);
        ushort2 m4 = *(const ushort2*)(Hf + (size_t)s4 * FOUT);
        ushort2 m5 = *(const ushort2*)(Hf + (size_t)s5 * FOUT);
        ushort2 m6 = *(const ushort2*)(Hf + (size_t)s6 * FOUT);
        ushort2 m7 = *(const ushort2*)(Hf + (size_t)s7 * FOUT);
        acc0 += v0 * bf2f(m0.x); acc1 += v0 * bf2f(m0.y);
        acc0 += v1 * bf2f(m1.x); acc1 += v1 * bf2f(m1.y);
        acc0 += v2 * bf2f(m2.x); acc1 += v2 * bf2f(m2.y);
        acc0 += v3 * bf2f(m3.x); acc1 += v3 * bf2f(m3.y);
        acc0 += v4 * bf2f(m4.x); acc1 += v4 * bf2f(m4.y);
        acc0 += v5 * bf2f(m5.x); acc1 += v5 * bf2f(m5.y);
        acc0 += v6 * bf2f(m6.x); acc1 += v6 * bf2f(m6.y);
        acc0 += v7 * bf2f(m7.x); acc1 += v7 * bf2f(m7.y);
    }
    for (; e + 2 <= e1; e += 2) {
        int   s0 = csr_src[e+0], s1 = csr_src[e+1];
        float v0 = csr_val[e+0], v1 = csr_val[e+1];
        ushort2 m0 = *(const ushort2*)(Hf + (size_t)s0 * FOUT);
        ushort2 m1 = *(const ushort2*)(Hf + (size_t)s1 * FOUT);
        acc0 += v0 * bf2f(m0.x); acc1 += v0 * bf2f(m0.y);
        acc0 += v1 * bf2f(m1.x); acc1 += v1 * bf2f(m1.y);
    }
    if (e < e1) {
        int   s0 = csr_src[e];
        float v0 = csr_val[e];
        ushort2 m0 = *(const ushort2*)(Hf + (size_t)s0 * FOUT);
        acc0 += v0 * bf2f(m0.x); acc1 += v0 * bf2f(m0.y);
    }

    acc0 += bias[2 * f2];
    acc1 += bias[2 * f2 + 1];
    if (RELU) { acc0 = fmaxf(acc0, 0.f); acc1 = fmaxf(acc1, 0.f); }
    if (OBF16) {
        ushort2 o = make_ushort2(f2bf(acc0), f2bf(acc1));
        *(ushort2*)((ushort_t*)outv + (size_t)node * FOUT + 2 * f2) = o;
    } else {
        *(float2*)((float*)outv + (size_t)node * FOUT + 2 * f2) = make_float2(acc0, acc1);
    }
}

// ---------------- launch ----------------

extern "C" void kernel_launch(void* const* d_in, const int* in_sizes, int n_in,
                              void* d_out, int out_size, void* d_ws, size_t ws_size,
                              hipStream_t stream) {
    const float* x    = (const float*)d_in[0];
    const int*   eidx = (const int*)d_in[1];
    const float* ea   = (const float*)d_in[2];
    const float* W1   = (const float*)d_in[3];
    const float* b1   = (const float*)d_in[4];
    const float* W2   = (const float*)d_in[5];
    const float* b2   = (const float*)d_in[6];
    const float* W3   = (const float*)d_in[7];
    const float* b3   = (const float*)d_in[8];

    const int N = in_sizes[0] / 128;
    const int E = in_sizes[2];

    const int nbins = (N + 255) >> BIN_SHIFT;            // 196 for N=50000 (<=256)
    const int epb   = (E + SCAT_NB - 1) / SCAT_NB;       // edges per scatter block
    const int nbc   = nbins * SCAT_NB;                   // bcnt/ebofs length
    const int gBC   = (nbc + BLK - 1) / BLK;

    char*  base = (char*)d_ws;
    size_t off  = 0;
    auto carve = [&](size_t nbytes) -> void* {
        void* p = base + off;
        off = (off + nbytes + 255) & ~(size_t)255;
        return p;
    };
    int*   bcnt      = (int*)  carve((size_t)nbc * 4);
    int*   ebofs     = (int*)  carve((size_t)nbc * 4);
    int*   bsumB     = (int*)  carve((size_t)512 * 4);
    int2*  binned_sd = (int2*) carve((size_t)E * 8);
    float* binned_ea = (float*)carve((size_t)E * 4);
    float* dinv      = (float*)carve((size_t)N * 4);
    float* selfn     = (float*)carve((size_t)N * 4);
    int*   cnt       = (int*)  carve((size_t)N * 4);
    int*   rowptr    = (int*)  carve((size_t)(N + 1) * 4);
    int*   bsum      = (int*)  carve((size_t)256 * 4);
    int*   csr_src   = (int*)  carve((size_t)E * 4);
    float* csr_val   = (float*)carve((size_t)E * 4);
    ushort_t* bufA   = (ushort_t*)carve((size_t)N * 128 * 2);   // bf16: gemm outputs H
    ushort_t* bufB   = (ushort_t*)carve((size_t)N * 128 * 2);   // bf16: xb / agg outputs G
    ushort_t* Wt1    = (ushort_t*)carve((size_t)128 * 128 * 2);
    ushort_t* Wt2    = (ushort_t*)carve((size_t)64 * 128 * 2);
    ushort_t* Wt3    = (ushort_t*)carve((size_t)32 * 64 * 2);
    (void)ws_size;

    const int gN = (N + BLK - 1) / BLK;   // 196 blocks (fits k_scan2's <=256)
    const int gR = (N + 63) / 64;         // MFMA gemm blocks (64 rows/block)

    // weight transpose+convert and x->bf16 (independent of CSR build)
    k_wconv<<<(128 * 128 + 255) / 256, BLK, 0, stream>>>(W1, Wt1, 128, 128);
    k_wconv<<<(128 * 64 + 255) / 256, BLK, 0, stream>>>(W2, Wt2, 128, 64);
    k_wconv<<<(64 * 32 + 255) / 256, BLK, 0, stream>>>(W3, Wt3, 64, 32);
    k_cvt<<<(N * 128 / 4 + 255) / 256, BLK, 0, stream>>>(x, bufB, N * 128 / 4);

    // binned CSR build (no global atomics)
    k_bin_count<<<SCAT_NB, BLK, 0, stream>>>(eidx, bcnt, nbins, epb, E);
    k_scan1<<<gBC, BLK, 0, stream>>>(bcnt, ebofs, bsumB, nbc);
    k_scan2x<<<1, BLK, 0, stream>>>(bsumB, gBC);
    k_scan3<<<gBC, BLK, 0, stream>>>(ebofs, bsumB, nbc);
    k_bin_scatter<<<SCAT_NB, BLK, 0, stream>>>(eidx, ea, ebofs, binned_sd, binned_ea, nbins, epb, E);
    k_bin_hist<<<nbins, BLK, 0, stream>>>(binned_sd, binned_ea, ebofs, cnt, dinv, selfn, nbins, N, E);
    k_scan1<<<gN, BLK, 0, stream>>>(cnt, rowptr, bsum, N);
    k_scan2<<<1, BLK, 0, stream>>>(bsum, rowptr, gN, N);
    k_scan3<<<gN, BLK, 0, stream>>>(rowptr, bsum, N);
    k_bin_emit<<<nbins, BLK, 0, stream>>>(binned_sd, binned_ea, ebofs, rowptr, dinv,
                                          csr_src, csr_val, nbins, E);

    // layer 1: 128 -> 128, relu
    k_gemm_mfma<128, 128><<<gR, BLK, 0, stream>>>(bufB, Wt1, bufA, N);
    k_agg<128, true, true><<<(N + 3) / 4, BLK, 0, stream>>>(bufA, selfn, rowptr, csr_src, csr_val, b1, bufB, N);

    // layer 2: 128 -> 64, relu
    k_gemm_mfma<128, 64><<<gR, BLK, 0, stream>>>(bufB, Wt2, bufA, N);
    k_agg<64, true, true><<<(N + 7) / 8, BLK, 0, stream>>>(bufA, selfn, rowptr, csr_src, csr_val, b2, bufB, N);

    // layer 3: 64 -> 32, no relu
    k_gemm_mfma<64, 32><<<gR, BLK, 0, stream>>>(bufB, Wt3, bufA, N);
    k_agg<32, false, false><<<(N + 15) / 16, BLK, 0, stream>>>(bufA, selfn, rowptr, csr_src, csr_val, b3, d_out, N);
}

// Round 10
// 156.835 us; speedup vs baseline: 1.5185x; 1.1784x over previous
//
#include <hip/hip_runtime.h>
#include <hip/hip_bf16.h>

#define BLK 256
#define SCAT_NB 512        // blocks in the binning scatter pass
#define BIN_SHIFT 8        // 256 nodes per bin

typedef unsigned short ushort_t;
typedef unsigned int uint_t;
typedef unsigned long long ull_t;
typedef __attribute__((ext_vector_type(8))) short bf16x8;
typedef __attribute__((ext_vector_type(4))) float f32x4;

static __device__ __forceinline__ float bf2f(ushort_t u) {
    return __uint_as_float((uint_t)u << 16);
}
static __device__ __forceinline__ ushort_t f2bf(float f) {
    __hip_bfloat16 h = __float2bfloat16(f);   // RNE
    return *reinterpret_cast<ushort_t*>(&h);
}

// ---------------- fused prologue: bin_count + weight conv + x->bf16 ----------------
// R9 post-mortem: pipeline is launch/serialization-overhead bound (19 dispatches,
// many <5us). Fused independent prologue work into one dispatch.

__global__ __launch_bounds__(256) void k_pre(const int* __restrict__ eidx,
                                             int* __restrict__ bcnt,
                                             int nbins, int epb, int E,
                                             const float* __restrict__ x,
                                             ushort_t* __restrict__ xb, int n4,
                                             const float* __restrict__ W1, ushort_t* __restrict__ Wt1,
                                             const float* __restrict__ W2, ushort_t* __restrict__ Wt2,
                                             const float* __restrict__ W3, ushort_t* __restrict__ Wt3) {
    const int b = blockIdx.x;
    const int t = threadIdx.x;
    if (b < SCAT_NB) {
        // per-(block,bin) edge counts
        __shared__ int h[256];
        h[t] = 0;
        __syncthreads();
        const int base = b * epb;
        const int lim  = min(base + epb, E);
        for (int e = base + t; e < lim; e += 256)
            atomicAdd(&h[eidx[E + e] >> BIN_SHIFT], 1);
        __syncthreads();
        if (t < nbins) bcnt[(size_t)t * SCAT_NB + b] = h[t];
    } else {
        int i = (b - SCAT_NB) * 256 + t;
        if (i < n4) {                       // x -> bf16, 4 elems/thread
            float4 v = ((const float4*)x)[i];
            ((ushort4*)xb)[i] = make_ushort4(f2bf(v.x), f2bf(v.y), f2bf(v.z), f2bf(v.w));
        } else {
            int j = i - n4;                 // W[fin][fout] -> Wt[fout][fin] bf16
            if (j < 128 * 128) {
                int r = j / 128, c = j % 128;
                Wt1[(size_t)c * 128 + r] = f2bf(W1[j]);
            } else if (j < 128 * 128 + 128 * 64) {
                j -= 128 * 128;
                int r = j / 64, c = j % 64;
                Wt2[(size_t)c * 128 + r] = f2bf(W2[j]);
            } else if (j < 128 * 128 + 128 * 64 + 64 * 32) {
                j -= 128 * 128 + 128 * 64;
                int r = j / 32, c = j % 32;
                Wt3[(size_t)c * 64 + r] = f2bf(W3[j]);
            }
        }
    }
}

// ---------------- scans for the bin-offset table ----------------

// per-block local exclusive scan of bcnt -> ebofs (block-local), block total -> bsum
__global__ __launch_bounds__(256) void k_scan1(const int* __restrict__ cnt,
                                               int* rowptr, int* bsum, int n) {
    __shared__ int tile[256];
    const int t = threadIdx.x;
    const int i = blockIdx.x * 256 + t;
    int v = (i < n) ? cnt[i] : 0;
    tile[t] = v;
    __syncthreads();
    for (int off = 1; off < 256; off <<= 1) {
        int x = (t >= off) ? tile[t - off] : 0;
        __syncthreads();
        tile[t] += x;
        __syncthreads();
    }
    if (i < n) rowptr[i] = tile[t] - v;
    if (t == 255) bsum[blockIdx.x] = tile[255];
}

// single block, arbitrary n (serial tiles with carry), in-place exclusive
__global__ __launch_bounds__(256) void k_scan2x(int* a, int n) {
    __shared__ int tile[256];
    __shared__ int carry_s;
    const int t = threadIdx.x;
    if (t == 0) carry_s = 0;
    __syncthreads();
    for (int base = 0; base < n; base += 256) {
        int i = base + t;
        int v = (i < n) ? a[i] : 0;
        tile[t] = v;
        __syncthreads();
        for (int off = 1; off < 256; off <<= 1) {
            int x = (t >= off) ? tile[t - off] : 0;
            __syncthreads();
            tile[t] += x;
            __syncthreads();
        }
        int carry = carry_s;
        if (i < n) a[i] = carry + tile[t] - v;
        __syncthreads();
        if (t == 255) carry_s = carry + tile[255];
        __syncthreads();
    }
}

// consumers reconstruct global offsets as ebofs[idx] + bsumB[idx>>8] (scan3 folded in)

// ---------------- binned CSR build ----------------

__global__ __launch_bounds__(256) void k_bin_scatter(const int* __restrict__ eidx,
                                                     const float* __restrict__ ea,
                                                     const int* __restrict__ ebofs,
                                                     const int* __restrict__ bsumB,
                                                     int2* __restrict__ binned_sd,
                                                     float* __restrict__ binned_ea,
                                                     int nbins, int epb, int E) {
    __shared__ int h[256];
    __shared__ int lofs[256];
    const int t = threadIdx.x;
    h[t] = 0;
    if (t < nbins) {
        int idx = t * SCAT_NB + blockIdx.x;
        lofs[t] = ebofs[idx] + bsumB[idx >> 8];
    }
    __syncthreads();
    const int base = blockIdx.x * epb;
    const int lim  = min(base + epb, E);
    for (int e = base + t; e < lim; e += 256) {
        int s = eidx[e];
        int d = eidx[E + e];
        float w = ea[e];
        int bin = d >> BIN_SHIFT;
        int r = atomicAdd(&h[bin], 1);      // LDS-local rank
        int pos = lofs[bin] + r;
        binned_sd[pos] = make_int2(s, d);
        binned_ea[pos] = w;
    }
}

// per-bin histogram -> dinv/selfn AND rowptr (LDS scan; bins are node-aligned,
// so rowptr[node] = bin_edge_start + exclusive_prefix(count within bin))
__global__ __launch_bounds__(256) void k_bin_hist(const int2* __restrict__ binned_sd,
                                                  const float* __restrict__ binned_ea,
                                                  const int* __restrict__ ebofs,
                                                  const int* __restrict__ bsumB,
                                                  float* __restrict__ dinv,
                                                  float* __restrict__ selfn,
                                                  int* __restrict__ rowptr,
                                                  int nbins, int N, int E) {
    __shared__ ull_t hs[256];
    __shared__ int sc[256];
    const int t = threadIdx.x;
    const int b = blockIdx.x;
    hs[t] = 0ull;
    __syncthreads();
    const int i0 = b * SCAT_NB;
    const int start = ebofs[i0] + bsumB[i0 >> 8];
    int end = E;
    if (b + 1 < nbins) {
        int i1 = (b + 1) * SCAT_NB;
        end = ebofs[i1] + bsumB[i1 >> 8];
    }
    for (int i = start + t; i < end; i += 256) {
        int d = binned_sd[i].y;
        float w = binned_ea[i];
        atomicAdd(&hs[d & 255], (1ull << 40) | (ull_t)(w * 4294967296.0f));
    }
    __syncthreads();
    int v = (int)(hs[t] >> 40);
    sc[t] = v;
    __syncthreads();
    for (int off = 1; off < 256; off <<= 1) {
        int x = (t >= off) ? sc[t - off] : 0;
        __syncthreads();
        sc[t] += x;
        __syncthreads();
    }
    const int node = (b << BIN_SHIFT) + t;
    if (node < N) {
        ull_t s = hs[t];
        float dg = 1.0f + (float)(s & ((1ull << 40) - 1)) * (1.0f / 4294967296.0f);
        dinv[node]  = rsqrtf(dg);
        selfn[node] = 1.0f / dg;
        rowptr[node] = start + sc[t] - v;
    }
    if (b == 0 && t == 0) rowptr[N] = E;
}

// per-bin emit into final (contiguous) CSR region
__global__ __launch_bounds__(256) void k_bin_emit(const int2* __restrict__ binned_sd,
                                                  const float* __restrict__ binned_ea,
                                                  const int* __restrict__ ebofs,
                                                  const int* __restrict__ bsumB,
                                                  const int* __restrict__ rowptr,
                                                  const float* __restrict__ dinv,
                                                  int* __restrict__ csr_src,
                                                  float* __restrict__ csr_val,
                                                  int nbins, int E) {
    __shared__ int c2[256];
    const int t = threadIdx.x;
    const int b = blockIdx.x;
    c2[t] = 0;
    __syncthreads();
    const int i0 = b * SCAT_NB;
    const int start = ebofs[i0] + bsumB[i0 >> 8];
    int end = E;
    if (b + 1 < nbins) {
        int i1 = (b + 1) * SCAT_NB;
        end = ebofs[i1] + bsumB[i1 >> 8];
    }
    for (int i = start + t; i < end; i += 256) {
        int2 sd = binned_sd[i];
        float w = binned_ea[i];
        int r = atomicAdd(&c2[sd.y & 255], 1);   // LDS-local rank within node
        int pos = rowptr[sd.y] + r;
        csr_src[pos] = sd.x;
        csr_val[pos] = dinv[sd.x] * w * dinv[sd.y];
    }
}

// ---------------- MFMA GEMM: C[n,FOUT](bf16) = A[n,FIN](bf16) @ Wt[FOUT,FIN]^T ----------------
// 32 rows/wave (2 row-groups share each B load -> 2x MFMA density, half the blocks).
// mfma_f32_16x16x32_bf16; A-frag row=lane&15 k=(lane>>4)*8+j; B-frag col=lane&15;
// C/D col=lane&15 row=(lane>>4)*4+reg (m89-verified mapping).

template <int FIN, int FOUT>
__global__ __launch_bounds__(256) void k_gemm_mfma(const ushort_t* __restrict__ A,
                                                   const ushort_t* __restrict__ Wt,
                                                   ushort_t* __restrict__ C, int n) {
    constexpr int NT = FOUT / 16;      // col tiles
    constexpr int NK = FIN / 32;       // K steps
    const int wave = threadIdx.x >> 6;
    const int lane = threadIdx.x & 63;
    const int r0 = (blockIdx.x * 4 + wave) * 32;
    if (r0 >= n) return;

    const int l15 = lane & 15;
    const int kg  = lane >> 4;
    const int arow0 = min(r0 + l15, n - 1);        // tail clamp; bad rows never stored
    const int arow1 = min(r0 + 16 + l15, n - 1);

    f32x4 acc0[NT], acc1[NT];
#pragma unroll
    for (int c = 0; c < NT; ++c) { acc0[c] = (f32x4)(0.0f); acc1[c] = (f32x4)(0.0f); }

    const ushort_t* Ap0 = A + (size_t)arow0 * FIN + kg * 8;
    const ushort_t* Ap1 = A + (size_t)arow1 * FIN + kg * 8;
    const ushort_t* Bp  = Wt + (size_t)l15 * FIN + kg * 8;

#pragma unroll 1   // keep rolled: full unroll hoists all B loads -> spill (R1 lesson)
    for (int ks = 0; ks < NK; ++ks) {
        bf16x8 a0 = *(const bf16x8*)(Ap0 + ks * 32);
        bf16x8 a1 = *(const bf16x8*)(Ap1 + ks * 32);
#pragma unroll
        for (int c = 0; c < NT; ++c) {
            bf16x8 bfr = *(const bf16x8*)(Bp + (size_t)c * 16 * FIN + ks * 32);
            acc0[c] = __builtin_amdgcn_mfma_f32_16x16x32_bf16(a0, bfr, acc0[c], 0, 0, 0);
            acc1[c] = __builtin_amdgcn_mfma_f32_16x16x32_bf16(a1, bfr, acc1[c], 0, 0, 0);
        }
    }

#pragma unroll
    for (int g = 0; g < 2; ++g) {
        const int rbase = r0 + g * 16 + kg * 4;
#pragma unroll
        for (int c = 0; c < NT; ++c) {
#pragma unroll
            for (int j = 0; j < 4; ++j) {
                int row = rbase + j;
                float val = (g == 0) ? acc0[c][j] : acc1[c][j];
                if (row < n) C[(size_t)row * FOUT + c * 16 + l15] = f2bf(val);
            }
        }
    }
}

// ---------------- aggregation (bf16 H, x8-unrolled gather loop) ----------------

template <int FOUT, bool RELU, bool OBF16>
__global__ __launch_bounds__(256) void k_agg(const ushort_t* __restrict__ H,
                                             const float* __restrict__ selfn,
                                             const int* __restrict__ rowptr,
                                             const int* __restrict__ csr_src,
                                             const float* __restrict__ csr_val,
                                             const float* __restrict__ bias,
                                             void* __restrict__ outv, int n) {
    constexpr int LPN = FOUT / 2;          // lanes per node: 64 / 32 / 16
    constexpr int NPW = 64 / LPN;          // nodes per wave: 1 / 2 / 4
    const int wave = threadIdx.x >> 6;
    const int lane = threadIdx.x & 63;
    const int sub  = lane / LPN;
    const int f2   = lane % LPN;           // feature-pair index
    const int node = (blockIdx.x * 4 + wave) * NPW + sub;
    if (node >= n) return;

    const ushort_t* __restrict__ Hf = H + 2 * f2;   // lane-fixed column base

    const float sn = selfn[node];
    ushort2 hv = *(const ushort2*)(Hf + (size_t)node * FOUT);
    float acc0 = sn * bf2f(hv.x);
    float acc1 = sn * bf2f(hv.y);

    const int e0 = rowptr[node], e1 = rowptr[node + 1];
    int e = e0;
    for (; e + 8 <= e1; e += 8) {
        int   s0 = csr_src[e+0], s1 = csr_src[e+1], s2 = csr_src[e+2], s3 = csr_src[e+3];
        int   s4 = csr_src[e+4], s5 = csr_src[e+5], s6 = csr_src[e+6], s7 = csr_src[e+7];
        float v0 = csr_val[e+0], v1 = csr_val[e+1], v2 = csr_val[e+2], v3 = csr_val[e+3];
        float v4 = csr_val[e+4], v5 = csr_val[e+5], v6 = csr_val[e+6], v7 = csr_val[e+7];
        ushort2 m0 = *(const ushort2*)(Hf + (size_t)s0 * FOUT);
        ushort2 m1 = *(const ushort2*)(Hf + (size_t)s1 * FOUT);
        ushort2 m2 = *(const ushort2*)(Hf + (size_t)s2 * FOUT);
        ushort2 m3 = *(const ushort2*)(Hf + (size_t)s3 * FOUT);
        ushort2 m4 = *(const ushort2*)(Hf + (size_t)s4 * FOUT);
        ushort2 m5 = *(const ushort2*)(Hf + (size_t)s5 * FOUT);
        ushort2 m6 = *(const ushort2*)(Hf + (size_t)s6 * FOUT);
        ushort2 m7 = *(const ushort2*)(Hf + (size_t)s7 * FOUT);
        acc0 += v0 * bf2f(m0.x); acc1 += v0 * bf2f(m0.y);
        acc0 += v1 * bf2f(m1.x); acc1 += v1 * bf2f(m1.y);
        acc0 += v2 * bf2f(m2.x); acc1 += v2 * bf2f(m2.y);
        acc0 += v3 * bf2f(m3.x); acc1 += v3 * bf2f(m3.y);
        acc0 += v4 * bf2f(m4.x); acc1 += v4 * bf2f(m4.y);
        acc0 += v5 * bf2f(m5.x); acc1 += v5 * bf2f(m5.y);
        acc0 += v6 * bf2f(m6.x); acc1 += v6 * bf2f(m6.y);
        acc0 += v7 * bf2f(m7.x); acc1 += v7 * bf2f(m7.y);
    }
    for (; e + 2 <= e1; e += 2) {
        int   s0 = csr_src[e+0], s1 = csr_src[e+1];
        float v0 = csr_val[e+0], v1 = csr_val[e+1];
        ushort2 m0 = *(const ushort2*)(Hf + (size_t)s0 * FOUT);
        ushort2 m1 = *(const ushort2*)(Hf + (size_t)s1 * FOUT);
        acc0 += v0 * bf2f(m0.x); acc1 += v0 * bf2f(m0.y);
        acc0 += v1 * bf2f(m1.x); acc1 += v1 * bf2f(m1.y);
    }
    if (e < e1) {
        int   s0 = csr_src[e];
        float v0 = csr_val[e];
        ushort2 m0 = *(const ushort2*)(Hf + (size_t)s0 * FOUT);
        acc0 += v0 * bf2f(m0.x); acc1 += v0 * bf2f(m0.y);
    }

    acc0 += bias[2 * f2];
    acc1 += bias[2 * f2 + 1];
    if (RELU) { acc0 = fmaxf(acc0, 0.f); acc1 = fmaxf(acc1, 0.f); }
    if (OBF16) {
        ushort2 o = make_ushort2(f2bf(acc0), f2bf(acc1));
        *(ushort2*)((ushort_t*)outv + (size_t)node * FOUT + 2 * f2) = o;
    } else {
        *(float2*)((float*)outv + (size_t)node * FOUT + 2 * f2) = make_float2(acc0, acc1);
    }
}

// ---------------- launch ----------------

extern "C" void kernel_launch(void* const* d_in, const int* in_sizes, int n_in,
                              void* d_out, int out_size, void* d_ws, size_t ws_size,
                              hipStream_t stream) {
    const float* x    = (const float*)d_in[0];
    const int*   eidx = (const int*)d_in[1];
    const float* ea   = (const float*)d_in[2];
    const float* W1   = (const float*)d_in[3];
    const float* b1   = (const float*)d_in[4];
    const float* W2   = (const float*)d_in[5];
    const float* b2   = (const float*)d_in[6];
    const float* W3   = (const float*)d_in[7];
    const float* b3   = (const float*)d_in[8];

    const int N = in_sizes[0] / 128;
    const int E = in_sizes[2];

    const int nbins = (N + 255) >> BIN_SHIFT;            // 196 for N=50000 (<=256)
    const int epb   = (E + SCAT_NB - 1) / SCAT_NB;       // edges per scatter block
    const int nbc   = nbins * SCAT_NB;                   // bcnt/ebofs length
    const int gBC   = (nbc + BLK - 1) / BLK;

    char*  base = (char*)d_ws;
    size_t off  = 0;
    auto carve = [&](size_t nbytes) -> void* {
        void* p = base + off;
        off = (off + nbytes + 255) & ~(size_t)255;
        return p;
    };
    int*   bcnt      = (int*)  carve((size_t)nbc * 4);
    int*   ebofs     = (int*)  carve((size_t)nbc * 4);
    int*   bsumB     = (int*)  carve((size_t)512 * 4);
    int2*  binned_sd = (int2*) carve((size_t)E * 8);
    float* binned_ea = (float*)carve((size_t)E * 4);
    float* dinv      = (float*)carve((size_t)N * 4);
    float* selfn     = (float*)carve((size_t)N * 4);
    int*   rowptr    = (int*)  carve((size_t)(N + 1) * 4);
    int*   csr_src   = (int*)  carve((size_t)E * 4);
    float* csr_val   = (float*)carve((size_t)E * 4);
    ushort_t* bufA   = (ushort_t*)carve((size_t)N * 128 * 2);   // bf16: gemm outputs H
    ushort_t* bufB   = (ushort_t*)carve((size_t)N * 128 * 2);   // bf16: xb / agg outputs G
    ushort_t* Wt1    = (ushort_t*)carve((size_t)128 * 128 * 2);
    ushort_t* Wt2    = (ushort_t*)carve((size_t)64 * 128 * 2);
    ushort_t* Wt3    = (ushort_t*)carve((size_t)32 * 64 * 2);
    (void)ws_size;

    const int n4 = N * 128 / 4;                          // float4 count for x->bf16
    const int gPre = SCAT_NB + (n4 + 128 * 128 + 128 * 64 + 64 * 32 + 255) / 256;
    const int gR = (N + 127) / 128;                      // MFMA gemm blocks (128 rows/block)

    // prologue: bin_count + weight transpose/convert + x->bf16 (one dispatch)
    k_pre<<<gPre, BLK, 0, stream>>>(eidx, bcnt, nbins, epb, E,
                                    x, bufB, n4, W1, Wt1, W2, Wt2, W3, Wt3);
    // scan bin offsets (global offsets reconstructed inline by consumers)
    k_scan1<<<gBC, BLK, 0, stream>>>(bcnt, ebofs, bsumB, nbc);
    k_scan2x<<<1, BLK, 0, stream>>>(bsumB, gBC);
    // binned CSR build (no global atomics); bin_hist also emits rowptr via LDS scan
    k_bin_scatter<<<SCAT_NB, BLK, 0, stream>>>(eidx, ea, ebofs, bsumB, binned_sd, binned_ea, nbins, epb, E);
    k_bin_hist<<<nbins, BLK, 0, stream>>>(binned_sd, binned_ea, ebofs, bsumB, dinv, selfn, rowptr, nbins, N, E);
    k_bin_emit<<<nbins, BLK, 0, stream>>>(binned_sd, binned_ea, ebofs, bsumB, rowptr, dinv,
                                          csr_src, csr_val, nbins, E);

    // layer 1: 128 -> 128, relu
    k_gemm_mfma<128, 128><<<gR, BLK, 0, stream>>>(bufB, Wt1, bufA, N);
    k_agg<128, true, true><<<(N + 3) / 4, BLK, 0, stream>>>(bufA, selfn, rowptr, csr_src, csr_val, b1, bufB, N);

    // layer 2: 128 -> 64, relu
    k_gemm_mfma<128, 64><<<gR, BLK, 0, stream>>>(bufB, Wt2, bufA, N);
    k_agg<64, true, true><<<(N + 7) / 8, BLK, 0, stream>>>(bufA, selfn, rowptr, csr_src, csr_val, b2, bufB, N);

    // layer 3: 64 -> 32, no relu
    k_gemm_mfma<64, 32><<<gR, BLK, 0, stream>>>(bufB, Wt3, bufA, N);
    k_agg<32, false, false><<<(N + 15) / 16, BLK, 0, stream>>>(bufA, selfn, rowptr, csr_src, csr_val, b3, d_out, N);
}